// Round 1
// baseline (1292.458 us; speedup 1.0000x reference)
//
#include <hip/hip_runtime.h>
#include <hip/hip_bf16.h>

namespace {

constexpr int CB   = 32;            // batch
constexpr int CS   = 64;            // seq len
constexpr int CDIN = 256;           // encoder hidden
constexpr int CH   = 256;           // LSTM hidden / GAT feature
constexpr int CE   = 128;           // embedding dim
constexpr int CV   = 128;           // vocab
constexpr int CGH  = 64;            // per-head GAT dim
constexpr int CNH  = 4;             // heads
constexpr int CN   = 128;           // graph nodes (1 token + 127 intents)
constexpr int CDX  = CDIN + CE;     // 384 LSTM input
constexpr int CG   = 4 * CH;        // 1024 gates
constexpr int CM   = CB * CS;       // 2048 tokens

__device__ __forceinline__ float leakyf(float x) { return x >= 0.f ? x : 0.2f * x; }
__device__ __forceinline__ float eluf(float x)   { return x > 0.f ? x : expm1f(x); }
__device__ __forceinline__ float sigmf(float x)  { return 1.f / (1.f + expf(-x)); }
__device__ __forceinline__ float wredf(float v) {
  #pragma unroll
  for (int off = 32; off; off >>= 1) v += __shfl_xor(v, off);
  return v;
}

// x[m, 0:256] = hidden[b,s,:]; x[m, 256:384] = (s==0 ? init : embedding[forced[b,s-1]])
__global__ void k_build_x(const float* __restrict__ hidden, const int* __restrict__ forced,
                          const float* __restrict__ emb, const float* __restrict__ initt,
                          float* __restrict__ x) {
  int idx = blockIdx.x * 256 + threadIdx.x;
  if (idx >= CM * CDX) return;
  int m = idx / CDX, d = idx - m * CDX;
  float v;
  if (d < CDIN) {
    v = hidden[m * CDIN + d];
  } else {
    int e = d - CDIN;
    v = (m % CS == 0) ? initt[e] : emb[forced[m - 1] * CE + e];
  }
  x[idx] = v;
}

// out[C][R] = in[R][C]^T
__global__ void k_transpose(const float* __restrict__ in, float* __restrict__ out,
                            int R, int C) {
  int idx = blockIdx.x * 256 + threadIdx.x;
  if (idx >= R * C) return;
  int c = idx / R, r = idx - c * R;
  out[idx] = in[r * C + c];
}

// hint[k][i][c] = intent[i] . Wh[k][:,c];  f1int/f2int[k][i] = hint . ah[k][0:64 / 64:128]
__global__ void k_hint(const float* __restrict__ intent, const float* __restrict__ Wh,
                       const float* __restrict__ ah, float* __restrict__ hint,
                       float* __restrict__ f1int, float* __restrict__ f2int) {
  int k = blockIdx.x / 127;
  int i = blockIdx.x % 127;
  int c = threadIdx.x;  // 64 threads
  float acc = 0.f;
  for (int d = 0; d < CH; ++d)
    acc += intent[i * CH + d] * Wh[(k * CH + d) * CGH + c];
  hint[(k * 128 + i) * CGH + c] = acc;
  float r1 = wredf(acc * ah[k * 128 + c]);
  float r2 = wredf(acc * ah[k * 128 + 64 + c]);
  if (c == 0) { f1int[k * 128 + i] = r1; f2int[k * 128 + i] = r2; }
}

// woao1[kk] = Wo[kk,:] . ao[0:256];  woao2[kk] = Wo[kk,:] . ao[256:512]
__global__ void k_woao(const float* __restrict__ Wo, const float* __restrict__ ao,
                       float* __restrict__ woao1, float* __restrict__ woao2) {
  int t = threadIdx.x;  // 512 threads
  if (t < CH) {
    float acc = 0.f;
    for (int c = 0; c < CH; ++c) acc += Wo[t * CH + c] * ao[c];
    woao1[t] = acc;
  } else {
    int tt = t - CH;
    float acc = 0.f;
    for (int c = 0; c < CH; ++c) acc += Wo[tt * CH + c] * ao[CH + c];
    woao2[tt] = acc;
  }
}

// xg[m,g] = x[m,:] . W_ihT[:,g] + b_ih[g] + b_hh[g]   (M=2048, K=384, N=1024)
__global__ void k_xg(const float* __restrict__ x, const float* __restrict__ WihT,
                     const float* __restrict__ bih, const float* __restrict__ bhh,
                     float* __restrict__ xg) {
  __shared__ float xs[8][CDX];
  int m0 = blockIdx.x * 8;
  int g = blockIdx.y * 256 + threadIdx.x;
  for (int idx = threadIdx.x; idx < 8 * CDX; idx += 256) {
    int r = idx / CDX, kk = idx - r * CDX;
    xs[r][kk] = x[(m0 + r) * CDX + kk];
  }
  __syncthreads();
  float bias = bih[g] + bhh[g];
  float acc[8];
  #pragma unroll
  for (int r = 0; r < 8; ++r) acc[r] = bias;
  #pragma unroll 4
  for (int kk = 0; kk < CDX; ++kk) {
    float w = WihT[kk * CG + g];
    #pragma unroll
    for (int r = 0; r < 8; ++r) acc[r] += w * xs[r][kk];
  }
  #pragma unroll
  for (int r = 0; r < 8; ++r) xg[(m0 + r) * CG + g] = acc[r];
}

// one block per batch element; 1024 threads = one gate each; 64 sequential steps
__global__ void k_lstm(const float* __restrict__ xg, const float* __restrict__ WhhT,
                       float* __restrict__ lo) {
  int b = blockIdx.x;
  int j = threadIdx.x;
  __shared__ float hs[CH];
  __shared__ float gbuf[CG];
  float c = 0.f;
  if (j < CH) hs[j] = 0.f;
  __syncthreads();
  for (int t = 0; t < CS; ++t) {
    float acc = xg[(b * CS + t) * CG + j];
    #pragma unroll 8
    for (int kk = 0; kk < CH; ++kk) acc += WhhT[kk * CG + j] * hs[kk];
    gbuf[j] = acc;
    __syncthreads();
    if (j < CH) {
      float gi = gbuf[j], gf = gbuf[CH + j], gg = gbuf[2 * CH + j], go = gbuf[3 * CH + j];
      c = sigmf(gf) * c + sigmf(gi) * tanhf(gg);
      float h = sigmf(go) * tanhf(c);
      hs[j] = h;
      lo[(b * CS + t) * CH + j] = h;
    }
    __syncthreads();
  }
}

// per (b,head): wS[i] = sum_{j>=1,adj} w_ij ; U[i][c] = sum_j w_ij * hint[j][c]   (rows i=1..127)
__global__ void k_U(const float* __restrict__ hint, const float* __restrict__ f1int,
                    const float* __restrict__ f2int, const int* __restrict__ adj,
                    float* __restrict__ U, float* __restrict__ wS) {
  int b = blockIdx.x >> 2, k = blockIdx.x & 3;
  int grp = threadIdx.x >> 6, c = threadIdx.x & 63;
  __shared__ float wbuf[4][128];
  const int adjb = b * CN * CN;
  for (int i = 1 + grp; i < 128; i += 4) {
    float f1 = f1int[k * 128 + (i - 1)];
    int j1 = 1 + c, j2 = 65 + c;
    float w1 = 0.f, w2 = 0.f;
    if (adj[adjb + i * CN + j1]) w1 = expf(leakyf(f1 + f2int[k * 128 + j1 - 1]));
    if (j2 < 128 && adj[adjb + i * CN + j2]) w2 = expf(leakyf(f1 + f2int[k * 128 + j2 - 1]));
    wbuf[grp][c] = w1;
    wbuf[grp][64 + c] = w2;              // slot 127 (c=63) = 0
    float rs = wredf(w1 + w2);
    float acc = 0.f;
    for (int jj = 0; jj < 127; ++jj)     // jj = j-1
      acc += wbuf[grp][jj] * hint[(k * 128 + jj) * CGH + c];
    if (c == 0) wS[(b * 4 + k) * 128 + i] = rs;
    U[((b * 4 + k) * 128 + i) * CGH + c] = acc;
  }
}

// htok[m, k*64+c] = lo[m,:] . Wh[k][:,c];  f1tok/f2tok[m,k] reductions
__global__ void k_htok(const float* __restrict__ lo, const float* __restrict__ Wh,
                       const float* __restrict__ ah, float* __restrict__ htok,
                       float* __restrict__ f1tok, float* __restrict__ f2tok) {
  __shared__ float ls[8][CH];
  int m0 = blockIdx.x * 8;
  int tid = threadIdx.x;
  int k = tid >> 6, c = tid & 63;
  for (int idx = tid; idx < 8 * CH; idx += 256) {
    int r = idx >> 8, d = idx & 255;
    ls[r][d] = lo[(m0 + r) * CH + d];
  }
  __syncthreads();
  float acc[8];
  #pragma unroll
  for (int r = 0; r < 8; ++r) acc[r] = 0.f;
  #pragma unroll 4
  for (int d = 0; d < CH; ++d) {
    float w = Wh[(k * CH + d) * CGH + c];
    #pragma unroll
    for (int r = 0; r < 8; ++r) acc[r] += w * ls[r][d];
  }
  float a1 = ah[k * 128 + c], a2 = ah[k * 128 + 64 + c];
  #pragma unroll
  for (int r = 0; r < 8; ++r) {
    htok[(m0 + r) * CH + tid] = acc[r];
    float r1 = wredf(acc[r] * a1);
    float r2 = wredf(acc[r] * a2);
    if (c == 0) { f1tok[(m0 + r) * CNH + k] = r1; f2tok[(m0 + r) * CNH + k] = r2; }
  }
}

// Fully fused per-token kernel: layer-1 rows (rank-1 update + row 0), layer-2 row 0
// via linearity, residual, logits. One block per token m, 256 threads.
__global__ void k_perm(const float* __restrict__ lo, const float* __restrict__ htok,
                       const float* __restrict__ f1tok, const float* __restrict__ f2tok,
                       const float* __restrict__ hint, const float* __restrict__ f1int,
                       const float* __restrict__ f2int, const float* __restrict__ U,
                       const float* __restrict__ wS, const float* __restrict__ woao1,
                       const float* __restrict__ woao2, const int* __restrict__ adj,
                       const float* __restrict__ Wo, const float* __restrict__ Wl,
                       const float* __restrict__ bl, const int* __restrict__ seq_lens,
                       float* __restrict__ out) {
  int m = blockIdx.x;
  int b = m >> 6, s = m & 63;
  int tid = threadIdx.x;
  int k = tid >> 6, c = tid & 63;

  __shared__ __hip_bfloat16 x1[CN][CH];  // 64 KB, layer-1 output (elu'd, heads concat)
  __shared__ float w0[CNH][CN];
  __shared__ float f22[CN];
  __shared__ float w2[CN];
  __shared__ float ybuf[CH];
  __shared__ float gbuf[CH];
  __shared__ float f12s, den2s;

  const int adjb = b * CN * CN;
  float ht  = htok[m * CH + tid];     // htok[m, k*64+c]
  float f1t = f1tok[m * CNH + k];
  float f2t = f2tok[m * CNH + k];

  // ---- layer-1 rows 1..127: rank-1 correction of precomputed (U, wS)
  for (int i = 1; i < CN; ++i) {
    float t0 = 0.f;
    if (adj[adjb + i * CN]) t0 = expf(leakyf(f1int[k * 128 + i - 1] + f2t));
    float den = wS[(b * 4 + k) * 128 + i] + t0;
    float val = (U[((b * 4 + k) * 128 + i) * CGH + c] + t0 * ht) / den;
    x1[i][tid] = __float2bfloat16(eluf(val));
  }

  // ---- layer-1 row 0 (full, per token)
  {
    int j1 = c, j2 = c + 64;
    float e1 = leakyf(f1t + (j1 == 0 ? f2t : f2int[k * 128 + j1 - 1]));
    float wj1 = adj[adjb + j1] ? expf(e1) : 0.f;
    float e2 = leakyf(f1t + f2int[k * 128 + j2 - 1]);
    float wj2 = adj[adjb + j2] ? expf(e2) : 0.f;
    w0[k][j1] = wj1;
    w0[k][j2] = wj2;
    float den0 = wredf(wj1 + wj2);          // all lanes hold row sum
    float acc = w0[k][0] * ht;              // in-wave LDS RAW: safe
    for (int j = 1; j < CN; ++j) acc += w0[k][j] * hint[(k * 128 + j - 1) * CGH + c];
    x1[0][tid] = __float2bfloat16(eluf(acc / den0));
  }
  __syncthreads();

  // ---- layer-2 attention scalars: f2_2[j] = x1[j,:] . (Wo@ao2); f1_2 = x1[0,:] . (Wo@ao1)
  {
    float wa0 = woao2[c], wa1 = woao2[64 + c], wa2 = woao2[128 + c], wa3 = woao2[192 + c];
    for (int j = k; j < CN; j += 4) {
      float p = __bfloat162float(x1[j][c]) * wa0
              + __bfloat162float(x1[j][64 + c]) * wa1
              + __bfloat162float(x1[j][128 + c]) * wa2
              + __bfloat162float(x1[j][192 + c]) * wa3;
      p = wredf(p);
      if (c == 0) f22[j] = p;
    }
    if (k == 0) {
      float p = __bfloat162float(x1[0][c]) * woao1[c]
              + __bfloat162float(x1[0][64 + c]) * woao1[64 + c]
              + __bfloat162float(x1[0][128 + c]) * woao1[128 + c]
              + __bfloat162float(x1[0][192 + c]) * woao1[192 + c];
      p = wredf(p);
      if (c == 0) f12s = p;
    }
  }
  __syncthreads();

  // ---- att2 row 0
  if (tid < CN) {
    float e = leakyf(f12s + f22[tid]);
    w2[tid] = adj[adjb + tid] ? expf(e) : 0.f;
  }
  __syncthreads();
  if (k == 0) {
    float v = wredf(w2[c] + w2[c + 64]);
    if (c == 0) den2s = v;
  }
  // y[col] = sum_j w2[j] * x1[j][col]   (undivided)
  float yacc = 0.f;
  for (int j = 0; j < CN; ++j) yacc += w2[j] * __bfloat162float(x1[j][tid]);
  ybuf[tid] = yacc;
  __syncthreads();

  // hp2[col] = (y @ Wo)[col] / den2 ; g = elu(hp2) + lo[m]
  float hacc = 0.f;
  #pragma unroll 4
  for (int kk = 0; kk < CH; ++kk) hacc += ybuf[kk] * Wo[kk * CH + tid];
  float g = eluf(hacc / den2s) + lo[m * CH + tid];
  gbuf[tid] = g;
  __syncthreads();

  // logits
  if (tid < CV) {
    float acc = bl[tid];
    #pragma unroll 4
    for (int cc = 0; cc < CH; ++cc) acc += gbuf[cc] * Wl[cc * CV + tid];
    out[m * CV + tid] = (s < seq_lens[b]) ? acc : 0.f;
  }
}

}  // namespace

extern "C" void kernel_launch(void* const* d_in, const int* in_sizes, int n_in,
                              void* d_out, int out_size, void* d_ws, size_t ws_size,
                              hipStream_t stream) {
  const float* hidden   = (const float*)d_in[0];
  const int*   seq_lens = (const int*)d_in[1];
  const int*   forced   = (const int*)d_in[2];
  const int*   adj      = (const int*)d_in[3];
  const float* intent   = (const float*)d_in[4];
  const float* emb      = (const float*)d_in[5];
  const float* initt    = (const float*)d_in[6];
  const float* W_ih     = (const float*)d_in[7];
  const float* W_hh     = (const float*)d_in[8];
  const float* b_ih     = (const float*)d_in[9];
  const float* b_hh     = (const float*)d_in[10];
  const float* Wh       = (const float*)d_in[11];
  const float* ah       = (const float*)d_in[12];
  const float* Wo       = (const float*)d_in[13];
  const float* ao       = (const float*)d_in[14];
  const float* Wl       = (const float*)d_in[15];
  const float* bl       = (const float*)d_in[16];
  float* out = (float*)d_out;

  float* ws    = (float*)d_ws;
  float* x     = ws;                       // 2048*384
  float* WihT  = x + CM * CDX;             // 384*1024
  float* WhhT  = WihT + CDX * CG;          // 256*1024
  float* xg    = WhhT + CH * CG;           // 2048*1024
  float* lo    = xg + CM * CG;             // 2048*256
  float* htok  = lo + CM * CH;             // 2048*256
  float* f1tok = htok + CM * CH;           // 2048*4
  float* f2tok = f1tok + CM * CNH;         // 2048*4
  float* hint  = f2tok + CM * CNH;         // 4*128*64
  float* f1int = hint + CNH * 128 * CGH;   // 4*128
  float* f2int = f1int + CNH * 128;        // 4*128
  float* U     = f2int + CNH * 128;        // 32*4*128*64
  float* wS    = U + CB * CNH * 128 * CGH; // 32*4*128
  float* woao1 = wS + CB * CNH * 128;      // 256
  float* woao2 = woao1 + CH;               // 256

  k_build_x<<<(CM * CDX + 255) / 256, 256, 0, stream>>>(hidden, forced, emb, initt, x);
  k_transpose<<<(CG * CDX + 255) / 256, 256, 0, stream>>>(W_ih, WihT, CG, CDX);
  k_transpose<<<(CG * CH + 255) / 256, 256, 0, stream>>>(W_hh, WhhT, CG, CH);
  k_hint<<<CNH * 127, 64, 0, stream>>>(intent, Wh, ah, hint, f1int, f2int);
  k_woao<<<1, 512, 0, stream>>>(Wo, ao, woao1, woao2);
  k_xg<<<dim3(CM / 8, CG / 256), 256, 0, stream>>>(x, WihT, b_ih, b_hh, xg);
  k_U<<<CB * CNH, 256, 0, stream>>>(hint, f1int, f2int, adj, U, wS);
  k_lstm<<<CB, 1024, 0, stream>>>(xg, WhhT, lo);
  k_htok<<<CM / 8, 256, 0, stream>>>(lo, Wh, ah, htok, f1tok, f2tok);
  k_perm<<<CM, 256, 0, stream>>>(lo, htok, f1tok, f2tok, hint, f1int, f2int,
                                 U, wS, woao1, woao2, adj, Wo, Wl, bl, seq_lens, out);
}